// Round 1
// baseline (627.974 us; speedup 1.0000x reference)
//
#include <hip/hip_runtime.h>
#include <cstdint>

typedef unsigned short u16;
typedef __attribute__((ext_vector_type(8))) __bf16 bf16x8_t;
typedef __attribute__((ext_vector_type(4))) float f32x4_t;

constexpr int Bn = 8, Tn = 4096, Dn = 1024, Hn = 1024;
constexpr int Mn = Bn * Tn;           // 32768 rows
constexpr int NC = 32, CL = Tn / NC;  // 32 chunks x 128 steps

__device__ __forceinline__ u16 f2bf(float f) {
  uint32_t u = __builtin_bit_cast(uint32_t, f);
  u += 0x7FFFu + ((u >> 16) & 1u);   // RNE; inputs are finite
  return (u16)(u >> 16);
}

__global__ __launch_bounds__(256) void cvt_bf16_kernel(const float* __restrict__ src,
                                                       u16* __restrict__ dst, int n4) {
  int i = blockIdx.x * 256 + threadIdx.x;
  if (i >= n4) return;
  float4 v = ((const float4*)src)[i];
  ushort4 o;
  o.x = f2bf(v.x); o.y = f2bf(v.y); o.z = f2bf(v.z); o.w = f2bf(v.w);
  ((ushort4*)dst)[i] = o;
}

__device__ __forceinline__ void gl_lds16(const void* g, void* l) {
  __builtin_amdgcn_global_load_lds((const __attribute__((address_space(1))) void*)g,
                                   (__attribute__((address_space(3))) void*)l, 16u, 0, 0u);
}

// NT GEMM: C[m,n] = sum_k A[m,k]*W[n,k] + bias[n].  A bf16 [M,1024], W bf16 [1024,1024].
// grid = (M/128, 16); blockIdx.y < 8 -> Wz/bz -> kout ; else Wh/bh -> thout
__global__ __launch_bounds__(256) void gemm_dual(
    const u16* __restrict__ A, const u16* __restrict__ Wz, const u16* __restrict__ Wh,
    const float* __restrict__ bz, const float* __restrict__ bh,
    float* __restrict__ kout, float* __restrict__ thout) {
  constexpr int K = 1024, N = 1024;
  int nb = blockIdx.y;
  const u16* Bm; const float* bias; float* Cout;
  if (nb < N / 128) { Bm = Wz; bias = bz; Cout = kout; }
  else             { Bm = Wh; bias = bh; Cout = thout; nb -= N / 128; }
  const int m0 = blockIdx.x * 128;
  const int n0 = nb * 128;

  __shared__ u16 lA[128 * 32];   // 8 KB, NO padding (global_load_lds lane mapping)
  __shared__ u16 lB[128 * 32];

  const int tid  = threadIdx.x;
  const int lane = tid & 63;
  const int wave = tid >> 6;
  const int wm = (wave >> 1) * 64;   // wave's 64x64 quadrant
  const int wn = (wave & 1) * 64;

  f32x4_t acc[4][4] = {};

  // staging: linear tile byte o = wave*1024 + lane*16 (+round*4096); elem e = o/2
  const int e0 = (wave * 1024 + lane * 16) >> 1;
  const int r0 = e0 >> 5, c0 = e0 & 31;
  const u16* gA0 = A  + (size_t)(m0 + r0) * K + c0;
  const u16* gB0 = Bm + (size_t)(n0 + r0) * K + c0;
  u16* lAw = lA + wave * 512;        // wave-uniform LDS dest base
  u16* lBw = lB + wave * 512;

  const int fr = lane & 15;          // fragment row (m or n)
  const int fk = (lane >> 4) * 8;    // fragment k offset

  for (int kt = 0; kt < K; kt += 32) {
    gl_lds16(gA0 + kt,           lAw);
    gl_lds16(gA0 + kt + 64 * K,  lAw + 2048);
    gl_lds16(gB0 + kt,           lBw);
    gl_lds16(gB0 + kt + 64 * K,  lBw + 2048);
    __syncthreads();   // drains vmcnt -> LDS valid
    bf16x8_t af[4], bfr[4];
#pragma unroll
    for (int i = 0; i < 4; ++i)
      af[i] = *(const bf16x8_t*)&lA[(wm + i * 16 + fr) * 32 + fk];
#pragma unroll
    for (int j = 0; j < 4; ++j)
      bfr[j] = *(const bf16x8_t*)&lB[(wn + j * 16 + fr) * 32 + fk];
#pragma unroll
    for (int i = 0; i < 4; ++i)
#pragma unroll
      for (int j = 0; j < 4; ++j)
        acc[i][j] = __builtin_amdgcn_mfma_f32_16x16x32_bf16(af[i], bfr[j], acc[i][j], 0, 0, 0);
    __syncthreads();   // all waves done with LDS before restage
  }

  // C/D layout: col = lane&15, row = (lane>>4)*4 + reg  [m89-verified]
  const int cr = (lane >> 4) * 4;
  const int cc = lane & 15;
#pragma unroll
  for (int j = 0; j < 4; ++j) {
    float bv = bias[n0 + wn + j * 16 + cc];
#pragma unroll
    for (int i = 0; i < 4; ++i) {
      float* p = Cout + (size_t)(m0 + wm + i * 16 + cr) * N + (n0 + wn + j * 16 + cc);
#pragma unroll
      for (int r = 0; r < 4; ++r)
        p[(size_t)r * N] = acc[i][j][r] + bv;
    }
  }
}

__device__ __forceinline__ void gates(float kv, float tv, float& a, float& bb) {
  float e = __expf(-kv);
  float z = 1.f / (1.f + e);     // sigmoid(k)
  a = e * z;                     // sigmoid(-k) = 1-z, no cancellation
  float g = (tv >= 0.f) ? (tv + 0.5f) : (1.f / (1.f + __expf(-tv)));
  bb = z * g;
}

// Phase A: per-chunk aggregates (A_c, B_c). grid (H/256, NC, B)
__global__ __launch_bounds__(256) void scan_phase_a(
    const float* __restrict__ kbuf, const float* __restrict__ thbuf,
    float* __restrict__ Aagg, float* __restrict__ Bagg) {
  int h = blockIdx.x * 256 + threadIdx.x;
  int c = blockIdx.y, b = blockIdx.z;
  size_t base = ((size_t)b * Tn + (size_t)c * CL) * Hn + h;
  float Aacc = 1.f, Bacc = 0.f;
#pragma unroll 4
  for (int t = 0; t < CL; ++t) {
    float a, bb;
    gates(kbuf[base + (size_t)t * Hn], thbuf[base + (size_t)t * Hn], a, bb);
    Aacc *= a;
    Bacc = fmaf(a, Bacc, bb);
  }
  size_t idx = ((size_t)b * NC + c) * Hn + h;
  Aagg[idx] = Aacc;
  Bagg[idx] = Bacc;
}

// Phase B: scan aggregates across chunks -> carry-in per chunk. grid (H/256, B)
__global__ __launch_bounds__(256) void scan_phase_b(
    const float* __restrict__ Aagg, const float* __restrict__ Bagg,
    float* __restrict__ carry) {
  int h = blockIdx.x * 256 + threadIdx.x;
  int b = blockIdx.y;
  float state = 0.f;
  for (int c = 0; c < NC; ++c) {
    size_t idx = ((size_t)b * NC + c) * Hn + h;
    carry[idx] = state;
    state = fmaf(Aagg[idx], state, Bagg[idx]);
  }
}

// Phase C: recompute gates, apply carry, write h. out MAY alias kbuf
// (same-thread load-before-store at identical index) -> no __restrict__ on those.
__global__ __launch_bounds__(256) void scan_phase_c(
    const float* kbuf, const float* __restrict__ thbuf,
    const float* __restrict__ carry, float* out) {
  int h = blockIdx.x * 256 + threadIdx.x;
  int c = blockIdx.y, b = blockIdx.z;
  float hst = carry[((size_t)b * NC + c) * Hn + h];
  size_t base = ((size_t)b * Tn + (size_t)c * CL) * Hn + h;
#pragma unroll 4
  for (int t = 0; t < CL; ++t) {
    size_t idx = base + (size_t)t * Hn;
    float kv = kbuf[idx];
    float tv = thbuf[idx];
    float a, bb;
    gates(kv, tv, a, bb);
    hst = fmaf(a, hst, bb);
    out[idx] = hst;
  }
}

extern "C" void kernel_launch(void* const* d_in, const int* in_sizes, int n_in,
                              void* d_out, int out_size, void* d_ws, size_t ws_size,
                              hipStream_t stream) {
  const float* x  = (const float*)d_in[0];
  const float* Wz = (const float*)d_in[1];
  const float* bz = (const float*)d_in[2];
  const float* Wh = (const float*)d_in[3];
  const float* bh = (const float*)d_in[4];
  float* out = (float*)d_out;

  // ws layout (bytes): xbf 64MB | wzbf 2MB | whbf 2MB | thbuf 128MB | Aagg 1MB | Bagg 1MB | carry 1MB
  char* ws = (char*)d_ws;
  u16*   xbf   = (u16*)  (ws);
  u16*   wzbf  = (u16*)  (ws + 67108864);
  u16*   whbf  = (u16*)  (ws + 69206016);
  float* thbuf = (float*)(ws + 71303168);
  float* Aagg  = (float*)(ws + 205520896);
  float* Bagg  = (float*)(ws + 206569472);
  float* carry = (float*)(ws + 207618048);
  float* kbuf  = out;  // k staged in d_out, overwritten in-place by phase C

  cvt_bf16_kernel<<<dim3(Mn * Dn / 4 / 256), 256, 0, stream>>>(x,  xbf,  Mn * Dn / 4);
  cvt_bf16_kernel<<<dim3(Hn * Dn / 4 / 256), 256, 0, stream>>>(Wz, wzbf, Hn * Dn / 4);
  cvt_bf16_kernel<<<dim3(Hn * Dn / 4 / 256), 256, 0, stream>>>(Wh, whbf, Hn * Dn / 4);
  gemm_dual<<<dim3(Mn / 128, 16), 256, 0, stream>>>(xbf, wzbf, whbf, bz, bh, kbuf, thbuf);
  scan_phase_a<<<dim3(Hn / 256, NC, Bn), 256, 0, stream>>>(kbuf, thbuf, Aagg, Bagg);
  scan_phase_b<<<dim3(Hn / 256, Bn),     256, 0, stream>>>(Aagg, Bagg, carry);
  scan_phase_c<<<dim3(Hn / 256, NC, Bn), 256, 0, stream>>>(kbuf, thbuf, carry, out);
}

// Round 2
// 502.257 us; speedup vs baseline: 1.2503x; 1.2503x over previous
//
#include <hip/hip_runtime.h>
#include <cstdint>

typedef unsigned short u16;
typedef __attribute__((ext_vector_type(8))) __bf16 bf16x8_t;
typedef __attribute__((ext_vector_type(4))) float f32x4_t;
typedef __attribute__((ext_vector_type(4))) _Float16 f16x4_t;

constexpr int Bn = 8, Tn = 4096, Dn = 1024, Hn = 1024;
constexpr int Mn = Bn * Tn;           // 32768 rows
constexpr int NC = 128, CL = Tn / NC; // 128 chunks x 32 steps

__device__ __forceinline__ u16 f2bf(float f) {
  uint32_t u = __builtin_bit_cast(uint32_t, f);
  u += 0x7FFFu + ((u >> 16) & 1u);   // RNE; inputs are finite
  return (u16)(u >> 16);
}

__global__ __launch_bounds__(256) void cvt_bf16_kernel(const float* __restrict__ src,
                                                       u16* __restrict__ dst, int n4) {
  int i = blockIdx.x * 256 + threadIdx.x;
  if (i >= n4) return;
  float4 v = ((const float4*)src)[i];
  ushort4 o;
  o.x = f2bf(v.x); o.y = f2bf(v.y); o.z = f2bf(v.z); o.w = f2bf(v.w);
  ((ushort4*)dst)[i] = o;
}

__device__ __forceinline__ void gl_lds16(const void* g, void* l) {
  __builtin_amdgcn_global_load_lds((const __attribute__((address_space(1))) void*)g,
                                   (__attribute__((address_space(3))) void*)l, 16u, 0, 0u);
}

// NT GEMM: C[m,n] = sum_k A[m,k]*W[n,k] + bias[n], C stored fp16.
// Flat 4096-block grid, XCD-aware swizzle: each XCD walks all 16 n-tiles of
// one m-slab before advancing -> A-slab fetched once per XCD window, W stays
// L2-resident.
__global__ __launch_bounds__(256) void gemm_dual(
    const u16* __restrict__ A, const u16* __restrict__ Wz, const u16* __restrict__ Wh,
    const float* __restrict__ bz, const float* __restrict__ bh,
    u16* __restrict__ kout, u16* __restrict__ thout) {
  constexpr int K = 1024, N = 1024;
  const uint bid = blockIdx.x;
  const uint xcd = bid & 7;
  const uint seq = bid >> 3;               // 0..511 per XCD
  uint nb = seq & 15;                      // n-tile, fastest per XCD
  const uint mt = (seq >> 4) * 8 + xcd;    // 0..255 m-tile
  const u16* Bm; const float* bias; u16* Cout;
  if (nb < N / 128) { Bm = Wz; bias = bz; Cout = kout; }
  else             { Bm = Wh; bias = bh; Cout = thout; nb -= N / 128; }
  const int m0 = mt * 128;
  const int n0 = nb * 128;

  __shared__ u16 lA[128 * 32];   // 8 KB, NO padding (global_load_lds lane mapping)
  __shared__ u16 lB[128 * 32];

  const int tid  = threadIdx.x;
  const int lane = tid & 63;
  const int wave = tid >> 6;
  const int wm = (wave >> 1) * 64;   // wave's 64x64 quadrant
  const int wn = (wave & 1) * 64;

  f32x4_t acc[4][4] = {};

  // staging: linear tile byte o = wave*1024 + lane*16 (+round*4096); elem e = o/2
  const int e0 = (wave * 1024 + lane * 16) >> 1;
  const int r0 = e0 >> 5, c0 = e0 & 31;
  const u16* gA0 = A  + (size_t)(m0 + r0) * K + c0;
  const u16* gB0 = Bm + (size_t)(n0 + r0) * K + c0;
  u16* lAw = lA + wave * 512;        // wave-uniform LDS dest base
  u16* lBw = lB + wave * 512;

  const int fr = lane & 15;          // fragment row (m or n)
  const int fk = (lane >> 4) * 8;    // fragment k offset

  for (int kt = 0; kt < K; kt += 32) {
    gl_lds16(gA0 + kt,           lAw);
    gl_lds16(gA0 + kt + 64 * K,  lAw + 2048);
    gl_lds16(gB0 + kt,           lBw);
    gl_lds16(gB0 + kt + 64 * K,  lBw + 2048);
    __syncthreads();   // drains vmcnt -> LDS valid
    bf16x8_t af[4], bfr[4];
#pragma unroll
    for (int i = 0; i < 4; ++i)
      af[i] = *(const bf16x8_t*)&lA[(wm + i * 16 + fr) * 32 + fk];
#pragma unroll
    for (int j = 0; j < 4; ++j)
      bfr[j] = *(const bf16x8_t*)&lB[(wn + j * 16 + fr) * 32 + fk];
#pragma unroll
    for (int i = 0; i < 4; ++i)
#pragma unroll
      for (int j = 0; j < 4; ++j)
        acc[i][j] = __builtin_amdgcn_mfma_f32_16x16x32_bf16(af[i], bfr[j], acc[i][j], 0, 0, 0);
    __syncthreads();   // all waves done with LDS before restage
  }

  // C/D layout: col = lane&15, row = (lane>>4)*4 + reg  [m89-verified]
  const int cr = (lane >> 4) * 4;
  const int cc = lane & 15;
#pragma unroll
  for (int j = 0; j < 4; ++j) {
    float bv = bias[n0 + wn + j * 16 + cc];
#pragma unroll
    for (int i = 0; i < 4; ++i) {
      u16* p = Cout + (size_t)(m0 + wm + i * 16 + cr) * N + (n0 + wn + j * 16 + cc);
#pragma unroll
      for (int r = 0; r < 4; ++r) {
        _Float16 hv = (_Float16)(acc[i][j][r] + bv);
        p[(size_t)r * N] = __builtin_bit_cast(u16, hv);
      }
    }
  }
}

__device__ __forceinline__ void gates(float kv, float tv, float& a, float& bb) {
  float e = __expf(-kv);
  float z = 1.f / (1.f + e);     // sigmoid(k)
  a = e * z;                     // sigmoid(-k) = 1-z, no cancellation
  float g = (tv >= 0.f) ? (tv + 0.5f) : (1.f / (1.f + __expf(-tv)));
  bb = z * g;
}

// Phase A: per-chunk aggregates. grid (NC, B), 256 thr, 4 h/thread (8B loads).
__global__ __launch_bounds__(256) void scan_phase_a(
    const u16* __restrict__ kbuf, const u16* __restrict__ thbuf,
    float* __restrict__ Aagg, float* __restrict__ Bagg) {
  int h0 = threadIdx.x * 4;
  int c = blockIdx.x, b = blockIdx.y;
  size_t base = ((size_t)b * Tn + (size_t)c * CL) * Hn + h0;
  f32x4_t Aacc = {1.f, 1.f, 1.f, 1.f};
  f32x4_t Bacc = {};
#pragma unroll 4
  for (int t = 0; t < CL; ++t) {
    f16x4_t kv = *(const f16x4_t*)(kbuf + base + (size_t)t * Hn);
    f16x4_t tv = *(const f16x4_t*)(thbuf + base + (size_t)t * Hn);
#pragma unroll
    for (int u = 0; u < 4; ++u) {
      float a, bb;
      gates((float)kv[u], (float)tv[u], a, bb);
      Aacc[u] *= a;
      Bacc[u] = fmaf(a, Bacc[u], bb);
    }
  }
  size_t idx = ((size_t)b * NC + c) * Hn + h0;
  *(f32x4_t*)(Aagg + idx) = Aacc;
  *(f32x4_t*)(Bagg + idx) = Bacc;
}

// Phase B: serial scan across chunks -> carry-in per chunk. grid (H/256, B).
// carry MAY alias Aagg: each idx is read (Av) before written (carry), same thread.
__global__ __launch_bounds__(256) void scan_phase_b(
    const float* Aagg, const float* __restrict__ Bagg, float* carry) {
  int h = blockIdx.x * 256 + threadIdx.x;
  int b = blockIdx.y;
  float state = 0.f;
  for (int c = 0; c < NC; ++c) {
    size_t idx = ((size_t)b * NC + c) * Hn + h;
    float Av = Aagg[idx];
    float Bv = Bagg[idx];
    carry[idx] = state;
    state = fmaf(Av, state, Bv);
  }
}

// Phase C: recompute gates, apply carry, write h (fp32). grid (NC, B).
__global__ __launch_bounds__(256) void scan_phase_c(
    const u16* __restrict__ kbuf, const u16* __restrict__ thbuf,
    const float* __restrict__ carry, float* __restrict__ out) {
  int h0 = threadIdx.x * 4;
  int c = blockIdx.x, b = blockIdx.y;
  f32x4_t hst = *(const f32x4_t*)(carry + ((size_t)b * NC + c) * Hn + h0);
  size_t base = ((size_t)b * Tn + (size_t)c * CL) * Hn + h0;
#pragma unroll 4
  for (int t = 0; t < CL; ++t) {
    size_t idx = base + (size_t)t * Hn;
    f16x4_t kv = *(const f16x4_t*)(kbuf + idx);
    f16x4_t tv = *(const f16x4_t*)(thbuf + idx);
#pragma unroll
    for (int u = 0; u < 4; ++u) {
      float a, bb;
      gates((float)kv[u], (float)tv[u], a, bb);
      hst[u] = fmaf(a, hst[u], bb);
    }
    *(f32x4_t*)(out + idx) = hst;
  }
}

extern "C" void kernel_launch(void* const* d_in, const int* in_sizes, int n_in,
                              void* d_out, int out_size, void* d_ws, size_t ws_size,
                              hipStream_t stream) {
  const float* x  = (const float*)d_in[0];
  const float* Wz = (const float*)d_in[1];
  const float* bz = (const float*)d_in[2];
  const float* Wh = (const float*)d_in[3];
  const float* bh = (const float*)d_in[4];
  float* out = (float*)d_out;

  // ws layout (bytes):
  //   xbf   64 MB @ 0
  //   wzbf   2 MB @ 67108864
  //   whbf   2 MB @ 69206016
  //   kf16  64 MB @ 71303168   ([M,H] fp16)
  //   thf16 64 MB @ 138412032
  //   Aagg   4 MB @ 205520896  ([B,NC,H] fp32; carry aliases this after phase B)
  //   Bagg   4 MB @ 209715200
  // total 204 MB
  char* ws = (char*)d_ws;
  u16*   xbf   = (u16*)  (ws);
  u16*   wzbf  = (u16*)  (ws + 67108864);
  u16*   whbf  = (u16*)  (ws + 69206016);
  u16*   kf16  = (u16*)  (ws + 71303168);
  u16*   thf16 = (u16*)  (ws + 138412032);
  float* Aagg  = (float*)(ws + 205520896);
  float* Bagg  = (float*)(ws + 209715200);
  float* carry = Aagg;  // safe alias (phase B reads before writing per idx)

  cvt_bf16_kernel<<<dim3(Mn * Dn / 4 / 256), 256, 0, stream>>>(x,  xbf,  Mn * Dn / 4);
  cvt_bf16_kernel<<<dim3(Hn * Dn / 4 / 256), 256, 0, stream>>>(Wz, wzbf, Hn * Dn / 4);
  cvt_bf16_kernel<<<dim3(Hn * Dn / 4 / 256), 256, 0, stream>>>(Wh, whbf, Hn * Dn / 4);
  gemm_dual<<<dim3(4096), 256, 0, stream>>>(xbf, wzbf, whbf, bz, bh, kf16, thf16);
  scan_phase_a<<<dim3(NC, Bn), 256, 0, stream>>>(kf16, thf16, Aagg, Bagg);
  scan_phase_b<<<dim3(Hn / 256, Bn), 256, 0, stream>>>(Aagg, Bagg, carry);
  scan_phase_c<<<dim3(NC, Bn), 256, 0, stream>>>(kf16, thf16, carry, out);
}

// Round 3
// 464.926 us; speedup vs baseline: 1.3507x; 1.0803x over previous
//
#include <hip/hip_runtime.h>
#include <cstdint>

typedef unsigned short u16;
typedef __attribute__((ext_vector_type(8))) __bf16 bf16x8_t;
typedef __attribute__((ext_vector_type(4))) float f32x4_t;

constexpr int Bn = 8, Tn = 4096, Dn = 1024, Hn = 1024;
constexpr int Mn = Bn * Tn;            // 32768 rows
constexpr int NC = 128, CL = Tn / NC;  // 128 chunks x 32 steps (chunk == one wave's rows)

__device__ __forceinline__ u16 f2bf(float f) {
  uint32_t u = __builtin_bit_cast(uint32_t, f);
  u += 0x7FFFu + ((u >> 16) & 1u);   // RNE; inputs finite
  return (u16)(u >> 16);
}

// single launch converts x, Wz, Wh to bf16
__global__ __launch_bounds__(256) void cvt_all(
    const float* __restrict__ x, const float* __restrict__ wz, const float* __restrict__ wh,
    u16* __restrict__ xb, u16* __restrict__ wzb, u16* __restrict__ whb) {
  int i = blockIdx.x * 256 + threadIdx.x;   // float4 index
  const float* s; u16* d; int off;
  if (i < 8388608)      { s = x;  d = xb;  off = i; }            // 32768*1024/4
  else if (i < 8650752) { s = wz; d = wzb; off = i - 8388608; }  // +1024*1024/4
  else                  { s = wh; d = whb; off = i - 8650752; }
  float4 v = ((const float4*)s)[off];
  ushort4 o;
  o.x = f2bf(v.x); o.y = f2bf(v.y); o.z = f2bf(v.z); o.w = f2bf(v.w);
  ((ushort4*)d)[off] = o;
}

__device__ __forceinline__ void gl_lds16(const void* g, void* l) {
  __builtin_amdgcn_global_load_lds((const __attribute__((address_space(1))) void*)g,
                                   (__attribute__((address_space(3))) void*)l, 16u, 0, 0u);
}

__device__ __forceinline__ void gates(float kv, float tv, float& a, float& bb) {
  float e  = __expf(-kv);
  float rc = __builtin_amdgcn_rcpf(1.f + e);   // z = sigmoid(k)
  a = e * rc;                                  // 1-z, no cancellation
  float g = (tv >= 0.f) ? (tv + 0.5f)
                        : __builtin_amdgcn_rcpf(1.f + __expf(-tv));
  bb = rc * g;
}

// Fused dual NT GEMM + gate epilogue + per-chunk scan aggregates.
// Block: 128 m-rows x 64 h-cols, BOTH projections (Wz and Wh).
// Wave w owns m-rows [w*32, w*32+32) = exactly chunk tc = (mt&31)*4 + w.
// LDS is source-side swizzled: lane loads global k-chunk (l&3)^((l>>3)&3) so
// fragment ds_read_b128 spreads over all 8 bank-groups (2-way = free, was 8-way).
__global__ __launch_bounds__(256) void gemm_fused(
    const u16* __restrict__ A, const u16* __restrict__ Wz, const u16* __restrict__ Wh,
    const float* __restrict__ bz, const float* __restrict__ bh,
    uint32_t* __restrict__ gAB, float* __restrict__ Aagg, float* __restrict__ Bagg) {
  constexpr int K = 1024;
  const uint bid = blockIdx.x;
  const uint xcd = bid & 7;
  const uint seq = bid >> 3;
  const uint ht  = seq & 15;               // 16 h-tiles fastest per XCD (W L2-resident)
  const uint mt  = (seq >> 4) * 8 + xcd;   // 256 m-tiles
  const int m0 = mt * 128;
  const int h0 = ht * 64;

  __shared__ u16 lA[128 * 32];     // 8 KB
  __shared__ u16 lB[2][64 * 32];   // 2 x 4 KB (Wz, Wh)

  const int tid  = threadIdx.x;
  const int lane = tid & 63;
  const int wave = tid >> 6;

  // ---- staging addresses (swizzled source column) ----
  const int csA = (((lane & 3) ^ ((lane >> 3) & 3)) * 8);   // elem offset
  const int csB = (((tid  & 3) ^ ((tid  >> 3) & 3)) * 8);
  const u16* gA0 = A  + (size_t)(m0 + wave * 16 + (lane >> 2)) * K + csA;
  const u16* gBz = Wz + (size_t)(h0 + (tid >> 2)) * K + csB;
  const u16* gBh = Wh + (size_t)(h0 + (tid >> 2)) * K + csB;
  u16* lAw  = lA    + wave * 512;   // wave-uniform LDS dest (u16 units)
  u16* lBw0 = lB[0] + wave * 512;
  u16* lBw1 = lB[1] + wave * 512;

  // ---- fragment read offsets (deswizzled) ----
  const int fr   = lane & 15;
  const int KB   = lane >> 4;
  const int fcol = (KB ^ ((fr >> 1) & 3)) * 8;   // u16 elems within row

  f32x4_t az[2][4] = {}, ah[2][4] = {};

  for (int kt = 0; kt < K; kt += 32) {
    gl_lds16(gA0 + kt,                    lAw);
    gl_lds16(gA0 + kt + (size_t)64 * K,   lAw + 2048);   // rows +64
    gl_lds16(gBz + kt,                    lBw0);
    gl_lds16(gBh + kt,                    lBw1);
    __syncthreads();
    bf16x8_t af[2], bzf[4], bhf[4];
#pragma unroll
    for (int i = 0; i < 2; ++i)
      af[i] = *(const bf16x8_t*)&lA[(wave * 32 + i * 16 + fr) * 32 + fcol];
#pragma unroll
    for (int j = 0; j < 4; ++j) {
      bzf[j] = *(const bf16x8_t*)&lB[0][(j * 16 + fr) * 32 + fcol];
      bhf[j] = *(const bf16x8_t*)&lB[1][(j * 16 + fr) * 32 + fcol];
    }
#pragma unroll
    for (int i = 0; i < 2; ++i)
#pragma unroll
      for (int j = 0; j < 4; ++j) {
        az[i][j] = __builtin_amdgcn_mfma_f32_16x16x32_bf16(af[i], bzf[j], az[i][j], 0, 0, 0);
        ah[i][j] = __builtin_amdgcn_mfma_f32_16x16x32_bf16(af[i], bhf[j], ah[i][j], 0, 0, 0);
      }
    __syncthreads();
  }

  // ---- epilogue: gates + packed store + ordered affine composition ----
  // C/D: col = lane&15, row = (lane>>4)*4 + reg  [m89-verified]
  const int cr = (lane >> 4) * 4;   // q*4
  const int cc = lane & 15;
  const int b  = mt >> 5;                    // batch
  const int tc = (mt & 31) * 4 + wave;       // chunk id (32 t-rows)

#pragma unroll
  for (int j = 0; j < 4; ++j) {
    float bvz = bz[h0 + j * 16 + cc];
    float bvh = bh[h0 + j * 16 + cc];
    float Ai[2], Bi[2];
#pragma unroll
    for (int i = 0; i < 2; ++i) {
      float Al = 1.f, Bl = 0.f;
#pragma unroll
      for (int r = 0; r < 4; ++r) {
        float kv = az[i][j][r] + bvz;
        float tv = ah[i][j][r] + bvh;
        float a, bb;
        gates(kv, tv, a, bb);
        _Float16 a16 = (_Float16)a, b16 = (_Float16)bb;
        uint32_t pk = (uint32_t)__builtin_bit_cast(u16, a16) |
                      ((uint32_t)__builtin_bit_cast(u16, b16) << 16);
        gAB[(size_t)(m0 + wave * 32 + i * 16 + cr + r) * Hn + h0 + j * 16 + cc] = pk;
        float ar = (float)a16, br = (float)b16;   // aggregate with the ROUNDED gates
        Al = Al * ar;
        Bl = fmaf(ar, Bl, br);
      }
      // ordered composition across lane-quads (rows ascend with q)
      float Ahi = __shfl_down(Al, 16), Bhi = __shfl_down(Bl, 16);
      float A2 = Ahi * Al;
      float B2 = fmaf(Ahi, Bl, Bhi);
      Ahi = __shfl_down(A2, 32); Bhi = __shfl_down(B2, 32);
      Ai[i] = Ahi * A2;
      Bi[i] = fmaf(Ahi, B2, Bhi);
    }
    float Aw = Ai[1] * Ai[0];                 // i=1 rows are later
    float Bw = fmaf(Ai[1], Bi[0], Bi[1]);
    if (lane < 16) {
      size_t ai = ((size_t)(b * NC + tc)) * Hn + h0 + j * 16 + lane;
      Aagg[ai] = Aw;
      Bagg[ai] = Bw;
    }
  }
}

// Phase B: serial scan of chunk aggregates -> carry per chunk. grid (16, B), 64 thr.
// carry MAY alias Aagg (read-before-write, same thread, same idx).
__global__ __launch_bounds__(64) void scan_phase_b(
    const float* Aagg, const float* __restrict__ Bagg, float* carry) {
  int h = blockIdx.x * 64 + threadIdx.x;
  int b = blockIdx.y;
  float state = 0.f;
  for (int c = 0; c < NC; ++c) {
    size_t idx = ((size_t)(b * NC + c)) * Hn + h;
    float Av = Aagg[idx];
    float Bv = Bagg[idx];
    carry[idx] = state;
    state = fmaf(Av, state, Bv);
  }
}

// Phase C: pure fma stream over packed fp16 gates. grid (NC, B), 256 thr, 4 h/thr.
__global__ __launch_bounds__(256) void scan_phase_c(
    const uint32_t* __restrict__ gAB, const float* __restrict__ carry,
    float* __restrict__ out) {
  int h0 = threadIdx.x * 4;
  int c = blockIdx.x, b = blockIdx.y;
  f32x4_t hst = *(const f32x4_t*)(carry + ((size_t)(b * NC + c)) * Hn + h0);
  size_t base = ((size_t)b * Tn + (size_t)c * CL) * Hn + h0;
#pragma unroll 4
  for (int t = 0; t < CL; ++t) {
    size_t idx = base + (size_t)t * Hn;
    uint4 v = *(const uint4*)(gAB + idx);
    uint32_t vv[4] = {v.x, v.y, v.z, v.w};
#pragma unroll
    for (int u = 0; u < 4; ++u) {
      float a = (float)__builtin_bit_cast(_Float16, (u16)(vv[u] & 0xFFFFu));
      float bb = (float)__builtin_bit_cast(_Float16, (u16)(vv[u] >> 16));
      hst[u] = fmaf(a, hst[u], bb);
    }
    *(f32x4_t*)(out + idx) = hst;
  }
}

extern "C" void kernel_launch(void* const* d_in, const int* in_sizes, int n_in,
                              void* d_out, int out_size, void* d_ws, size_t ws_size,
                              hipStream_t stream) {
  const float* x  = (const float*)d_in[0];
  const float* Wz = (const float*)d_in[1];
  const float* bz = (const float*)d_in[2];
  const float* Wh = (const float*)d_in[3];
  const float* bh = (const float*)d_in[4];
  float* out = (float*)d_out;

  // ws layout (bytes):
  //   xbf   64 MB @ 0
  //   wzbf   2 MB @ 67108864
  //   whbf   2 MB @ 69206016
  //   gAB  128 MB @ 71303168   ([M,H] u32 = fp16 a | b<<16)
  //   Aagg   4 MB @ 205520896  ([B,NC,H] fp32; carry aliases after phase B)
  //   Bagg   4 MB @ 209715200
  char* ws = (char*)d_ws;
  u16*      xbf   = (u16*)     (ws);
  u16*      wzbf  = (u16*)     (ws + 67108864);
  u16*      whbf  = (u16*)     (ws + 69206016);
  uint32_t* gAB   = (uint32_t*)(ws + 71303168);
  float*    Aagg  = (float*)   (ws + 205520896);
  float*    Bagg  = (float*)   (ws + 209715200);
  float*    carry = Aagg;   // safe alias

  cvt_all<<<dim3(34816), 256, 0, stream>>>(x, Wz, Wh, xbf, wzbf, whbf);
  gemm_fused<<<dim3(4096), 256, 0, stream>>>(xbf, wzbf, whbf, bz, bh, gAB, Aagg, Bagg);
  scan_phase_b<<<dim3(16, Bn), 64, 0, stream>>>(Aagg, Bagg, carry);
  scan_phase_c<<<dim3(NC, Bn), 256, 0, stream>>>(gAB, carry, out);
}